// Round 6
// baseline (1257.237 us; speedup 1.0000x reference)
//
#include <hip/hip_runtime.h>
#include <hip/hip_bf16.h>

#define M_ 4096
#define N_ 32000
#define K_ 4096
#define S_ 2048
#define SM1 2047
#define NROWS 4094
#define NT_ 64  // K-tiles of BK=64

typedef __bf16 bf16x8 __attribute__((ext_vector_type(8)));
typedef float f32x4 __attribute__((ext_vector_type(4)));

#define GLDS16(g, l)                                                         \
  __builtin_amdgcn_global_load_lds(                                          \
      (__attribute__((address_space(1))) const void*)(g),                    \
      (__attribute__((address_space(3))) void*)(l), 16, 0, 0)
#define BAR() __builtin_amdgcn_s_barrier()
#define PRIO1() __builtin_amdgcn_s_setprio(1)
#define PRIO0() __builtin_amdgcn_s_setprio(0)
#define VMCNT(n) asm volatile("s_waitcnt vmcnt(" #n ")" ::: "memory")

// ---------------------------------------------------------------- cvt kernel
__global__ __launch_bounds__(256) void cvt_f32_to_bf16(
    const float* __restrict__ in, bf16x8* __restrict__ out, long n8) {
  long i0 = (long)blockIdx.x * blockDim.x + threadIdx.x;
  long stride = (long)gridDim.x * blockDim.x;
  for (long i = i0; i < n8; i += stride) {
    const float4* p = reinterpret_cast<const float4*>(in) + i * 2;
    float4 a = p[0];
    float4 b = p[1];
    bf16x8 v;
    v[0] = (__bf16)a.x; v[1] = (__bf16)a.y; v[2] = (__bf16)a.z; v[3] = (__bf16)a.w;
    v[4] = (__bf16)b.x; v[5] = (__bf16)b.y; v[6] = (__bf16)b.z; v[7] = (__bf16)b.w;
    out[i] = v;
  }
}

// ---------------------------------------------------------------- GEMM 256x256, BK=64, overlap schedule v3
// C[m,n] = sum_k A[m,k]*B[n,k]. 512 thr = 8 waves (2m x 4n), per-wave 128x64
// = acc[8][4]. LDS 2 x 64KB (A 32K | B 32K), 128-B rows, slot = c ^ (row&7)
// (measured-conflict-free pair: linear GLDS dest + inverse-swz source).
//
// Halfsets (2 GLDS/thread each):
//   SA0 = A rows bit6==0 (a_lo)   SA1 = A rows bit6==1 (a_hi)
//   SB0 = B rows bit5==0 (b0)     SB1 = B rows bit5==1 (b1)
// v3 = full one-phase-ahead ds_read pipelining. Tile s (4 barriers):
//   ph1: stage SA0(s+1); MFMA al*b0; VMCNT(2) [SA1,SB1(s) landed]; BAR
//   ph2: stage SB0(s+1); read b1r(s),ah(s); MFMA al*b1 (ah drains under); BAR
//   ph3: stage SA1(s+1); MFMA ah*b0; VMCNT(2) [SA0,SB0(s+1) landed]; BAR
//   ph4: stage SB1(s+1); read b0r(s+1),al(s+1) (drain under MFMA);
//        MFMA ah*b1; BAR      <- no boundary wait, no boundary reads
// vmcnt audit (in-order, steady): ph1-end queue = [SA1(s),SB1(s),SA0(s+1)]=6
// -> VMCNT(2) retires SA1,SB1(s). ph3-end queue = [SA0(s+1),SB0(s+1),
// SA1(s+1)]=6 -> VMCNT(2) retires SA0,SB0(s+1). Tail (s=NT-1, no staging):
// ph1 VMCNT(0) retires SA1,SB1(NT-1); ph3 skip; ph4 no reads.
// Collective rule: every cross-wave LDS read is after a BAR preceded by the
// covering VMCNT in all waves. WAR: each region's overwrite is >=4 barriers
// after its last reader's lgkm-complete.
__global__ __launch_bounds__(512, 2) void gemm256(
    const __bf16* __restrict__ A, const __bf16* __restrict__ B,
    float* __restrict__ C) {
  __shared__ __align__(1024) unsigned char smem[2][65536];

  const int tid = threadIdx.x;
  const int bid = blockIdx.x;
  // Bijective XCD swizzle (2000 % 8 == 0), n-panel-major within XCD.
  const int wg = (bid & 7) * 250 + (bid >> 3);
  const int nblk = wg >> 4;  // 0..124
  const int mblk = wg & 15;  // 0..15
  const int m0 = mblk * 256;
  const int n0 = nblk * 256;

  const int w = tid >> 6;
  const int lane = tid & 63;
  const int wm = w >> 2;  // 0..1
  const int wn = w & 3;   // 0..3
  const int rl = lane & 15;
  const int cl = lane >> 4;
  const int srow = tid >> 3;  // staging row-within-64 block
  const int scc = tid & 7;    // staging dest chunk

  f32x4 acc[8][4];
#pragma unroll
  for (int i = 0; i < 8; ++i)
#pragma unroll
    for (int j = 0; j < 4; ++j) acc[i][j] = (f32x4){0.f, 0.f, 0.f, 0.f};

  // A halfset q: 64-row blocks at q*64 and 128+q*64.
  auto stA2 = [&](int nbuf, int kt, int q) {
#pragma unroll
    for (int j = 0; j < 2; ++j) {
      const int r0 = q * 64 + j * 128;
      const int row = r0 + srow;
      const int c = scc ^ (row & 7);
      GLDS16(A + (size_t)(m0 + row) * K_ + kt * 64 + c * 8,
             &smem[nbuf][r0 * 128 + tid * 16]);
    }
  };
  // B halfset q: 32-row stripes at {0,64,128,192}+q*32.
  auto stB2 = [&](int nbuf, int kt, int q) {
#pragma unroll
    for (int j = 0; j < 2; ++j) {
      const int cg = j * 512 + tid;
      const int rl_ = cg >> 3;
      const int row = ((rl_ >> 5) << 6) + q * 32 + (rl_ & 31);
      const int cc = cg & 7;
      const int c = cc ^ (row & 7);
      GLDS16(B + (size_t)(n0 + row) * K_ + kt * 64 + c * 8,
             &smem[nbuf][32768 + row * 128 + cc * 16]);
    }
  };
  auto ld = [&](const unsigned char* base, int row, int c) -> bf16x8 {
    return *(const bf16x8*)(base + row * 128 + (((c ^ row) & 7) << 4));
  };

  // Prologue: tile 0 halfsets in consumption order; collective wait SA0,SB0.
  stA2(0, 0, 0); stB2(0, 0, 0); stA2(0, 0, 1); stB2(0, 0, 1);
  VMCNT(4);
  BAR();

  bf16x8 al[4][2], ah[4][2], b0r[2][2], b1r[2][2];
#pragma unroll
  for (int jj = 0; jj < 2; ++jj)
#pragma unroll
    for (int ks = 0; ks < 2; ++ks)
      b0r[jj][ks] = ld(smem[0] + 32768, wn * 64 + jj * 16 + rl, ks * 4 + cl);
#pragma unroll
  for (int ii = 0; ii < 4; ++ii)
#pragma unroll
    for (int ks = 0; ks < 2; ++ks)
      al[ii][ks] = ld(smem[0], wm * 128 + ii * 16 + rl, ks * 4 + cl);

  for (int s = 0; s < NT_; ++s) {
    const int cur = s & 1;
    const int nxt = cur ^ 1;
    const unsigned char* bA = smem[cur];
    const unsigned char* bB = smem[cur] + 32768;
    const bool st = (s + 1 < NT_);

    // ---- ph1: stage SA0(s+1); MFMA a_lo x b0; collective wait SA1,SB1(s)
    if (st) stA2(nxt, s + 1, 0);
    PRIO1();
#pragma unroll
    for (int ii = 0; ii < 4; ++ii)
#pragma unroll
      for (int jj = 0; jj < 2; ++jj)
#pragma unroll
        for (int ks = 0; ks < 2; ++ks)
          acc[ii][jj] = __builtin_amdgcn_mfma_f32_16x16x32_bf16(
              al[ii][ks], b0r[jj][ks], acc[ii][jj], 0, 0, 0);
    PRIO0();
    if (st) { VMCNT(2); } else { VMCNT(0); }
    BAR();

    // ---- ph2: stage SB0(s+1); read b1(first)+a_hi; MFMA a_lo x b1
    if (st) stB2(nxt, s + 1, 0);
#pragma unroll
    for (int jj = 0; jj < 2; ++jj)
#pragma unroll
      for (int ks = 0; ks < 2; ++ks)
        b1r[jj][ks] = ld(bB, wn * 64 + 32 + jj * 16 + rl, ks * 4 + cl);
#pragma unroll
    for (int ii = 0; ii < 4; ++ii)
#pragma unroll
      for (int ks = 0; ks < 2; ++ks)
        ah[ii][ks] = ld(bA, wm * 128 + 64 + ii * 16 + rl, ks * 4 + cl);
    PRIO1();
#pragma unroll
    for (int ii = 0; ii < 4; ++ii)
#pragma unroll
      for (int jj = 0; jj < 2; ++jj)
#pragma unroll
        for (int ks = 0; ks < 2; ++ks)
          acc[ii][2 + jj] = __builtin_amdgcn_mfma_f32_16x16x32_bf16(
              al[ii][ks], b1r[jj][ks], acc[ii][2 + jj], 0, 0, 0);
    PRIO0();
    BAR();

    // ---- ph3: stage SA1(s+1); MFMA a_hi x b0; collective wait SA0,SB0(s+1)
    if (st) stA2(nxt, s + 1, 1);
    PRIO1();
#pragma unroll
    for (int ii = 0; ii < 4; ++ii)
#pragma unroll
      for (int jj = 0; jj < 2; ++jj)
#pragma unroll
        for (int ks = 0; ks < 2; ++ks)
          acc[4 + ii][jj] = __builtin_amdgcn_mfma_f32_16x16x32_bf16(
              ah[ii][ks], b0r[jj][ks], acc[4 + ii][jj], 0, 0, 0);
    PRIO0();
    if (st) VMCNT(2);
    BAR();

    // ---- ph4: stage SB1(s+1); read next b0,a_lo (drain under MFMA);
    //           MFMA a_hi x b1; BAR (no boundary wait)
    if (st) stB2(nxt, s + 1, 1);
    if (st) {
      const unsigned char* nA = smem[nxt];
      const unsigned char* nB = smem[nxt] + 32768;
#pragma unroll
      for (int jj = 0; jj < 2; ++jj)
#pragma unroll
        for (int ks = 0; ks < 2; ++ks)
          b0r[jj][ks] = ld(nB, wn * 64 + jj * 16 + rl, ks * 4 + cl);
#pragma unroll
      for (int ii = 0; ii < 4; ++ii)
#pragma unroll
        for (int ks = 0; ks < 2; ++ks)
          al[ii][ks] = ld(nA, wm * 128 + ii * 16 + rl, ks * 4 + cl);
    }
    PRIO1();
#pragma unroll
    for (int ii = 0; ii < 4; ++ii)
#pragma unroll
      for (int jj = 0; jj < 2; ++jj)
#pragma unroll
        for (int ks = 0; ks < 2; ++ks)
          acc[4 + ii][2 + jj] = __builtin_amdgcn_mfma_f32_16x16x32_bf16(
              ah[ii][ks], b1r[jj][ks], acc[4 + ii][2 + jj], 0, 0, 0);
    PRIO0();
    BAR();
  }

  // Epilogue: C/D layout col = lane&15, row = (lane>>4)*4 + reg  [m89]
#pragma unroll
  for (int i = 0; i < 8; ++i)
#pragma unroll
    for (int j = 0; j < 4; ++j)
#pragma unroll
      for (int r = 0; r < 4; ++r) {
        const int grow = m0 + wm * 128 + i * 16 + cl * 4 + r;
        const int gcol = n0 + wn * 64 + j * 16 + rl;
        C[(size_t)grow * N_ + gcol] = acc[i][j][r];
      }
}

// ---------------------------------------------------------------- fallback GEMM (fp32 in, 128^2)
__global__ __launch_bounds__(256) void gemm_fb(const float* __restrict__ Ap,
                                               const float* __restrict__ Bp,
                                               float* __restrict__ Cp) {
  __shared__ __align__(1024) unsigned char smem[2][16384];
  const int tid = threadIdx.x;
  const int bid = blockIdx.x;
  const int swz = (bid & 7) * 1000 + (bid >> 3);
  const int nblk = swz >> 5;
  const int mblk = swz & 31;
  const int m0 = mblk * 128;
  const int n0 = nblk * 128;
  const int w = tid >> 6, lane = tid & 63;
  const int wm = w >> 1, wn = w & 1;
  const int rl = lane & 15, cl = lane >> 4;

  f32x4 acc[4][4];
#pragma unroll
  for (int i = 0; i < 4; ++i)
#pragma unroll
    for (int j = 0; j < 4; ++j) acc[i][j] = (f32x4){0.f, 0.f, 0.f, 0.f};

  auto stage = [&](int buf, int kt) {
    const int k0 = kt * 32;
#pragma unroll
    for (int j = 0; j < 2; ++j) {
      const int t = j * 256 + tid;
      const int row = t >> 2;
      const int c = t & 3;
      const int rp = row >> 1;
      const int pp = ((row & 1) * 4 + c) ^ (rp & 7);
      const int lb = rp * 128 + pp * 16;
      {
        const float4* g = (const float4*)(Ap + (size_t)(m0 + row) * K_ + k0 + c * 8);
        float4 x = g[0], y = g[1];
        bf16x8 v;
        v[0] = (__bf16)x.x; v[1] = (__bf16)x.y; v[2] = (__bf16)x.z; v[3] = (__bf16)x.w;
        v[4] = (__bf16)y.x; v[5] = (__bf16)y.y; v[6] = (__bf16)y.z; v[7] = (__bf16)y.w;
        *(bf16x8*)(&smem[buf][lb]) = v;
      }
      {
        const float4* g = (const float4*)(Bp + (size_t)(n0 + row) * K_ + k0 + c * 8);
        float4 x = g[0], y = g[1];
        bf16x8 v;
        v[0] = (__bf16)x.x; v[1] = (__bf16)x.y; v[2] = (__bf16)x.z; v[3] = (__bf16)x.w;
        v[4] = (__bf16)y.x; v[5] = (__bf16)y.y; v[6] = (__bf16)y.z; v[7] = (__bf16)y.w;
        *(bf16x8*)(&smem[buf][8192 + lb]) = v;
      }
    }
  };
  auto ldfrag = [&](const unsigned char* base, int row, int c) -> bf16x8 {
    const int rp = row >> 1;
    const int pp = ((row & 1) * 4 + c) ^ (rp & 7);
    return *(const bf16x8*)(base + rp * 128 + pp * 16);
  };
  auto compute = [&](int buf) {
    const unsigned char* bA = smem[buf];
    const unsigned char* bB = smem[buf] + 8192;
    bf16x8 af[4], bfv[4];
#pragma unroll
    for (int i = 0; i < 4; ++i) af[i] = ldfrag(bA, wm * 64 + i * 16 + rl, cl);
#pragma unroll
    for (int j = 0; j < 4; ++j) bfv[j] = ldfrag(bB, wn * 64 + j * 16 + rl, cl);
#pragma unroll
    for (int i = 0; i < 4; ++i)
#pragma unroll
      for (int j = 0; j < 4; ++j)
        acc[i][j] = __builtin_amdgcn_mfma_f32_16x16x32_bf16(af[i], bfv[j],
                                                            acc[i][j], 0, 0, 0);
  };

  stage(0, 0);
  __syncthreads();
  for (int kt = 0; kt < 128; kt += 2) {
    if (kt + 1 < 128) stage(1, kt + 1);
    compute(0);
    __syncthreads();
    if (kt + 2 < 128) stage(0, kt + 2);
    compute(1);
    __syncthreads();
  }
#pragma unroll
  for (int i = 0; i < 4; ++i)
#pragma unroll
    for (int j = 0; j < 4; ++j)
#pragma unroll
      for (int r = 0; r < 4; ++r) {
        const int grow = m0 + wm * 64 + i * 16 + cl * 4 + r;
        const int gcol = n0 + wn * 64 + j * 16 + rl;
        Cp[(size_t)grow * N_ + gcol] = acc[i][j][r];
      }
}

// ---------------------------------------------------------------- CE loss (online, 1-pass)
__global__ __launch_bounds__(256) void ce_rows(const float* __restrict__ logits,
                                               const int* __restrict__ labels,
                                               float* __restrict__ nll) {
  const int r = blockIdx.x;
  const int b = r / SM1;
  const int t = r - b * SM1;
  const float* row = logits + (size_t)(b * S_ + t) * N_;
  float m = -3.4e38f, s = 0.f;
  const float4* row4 = (const float4*)row;
  for (int i = threadIdx.x; i < 7936; i += 256) {  // 7936*4 = 31744
    float4 v = row4[i];
    float mx = fmaxf(fmaxf(v.x, v.y), fmaxf(v.z, v.w));
    if (mx > m) { s *= __expf(m - mx); m = mx; }
    s += __expf(v.x - m) + __expf(v.y - m) + __expf(v.z - m) + __expf(v.w - m);
  }
  {  // remainder: 256 elements
    float v = row[31744 + threadIdx.x];
    if (v > m) { s *= __expf(m - v); m = v; }
    s += __expf(v - m);
  }
#pragma unroll
  for (int o = 32; o > 0; o >>= 1) {
    float m2 = __shfl_xor(m, o), s2 = __shfl_xor(s, o);
    float mn = fmaxf(m, m2);
    s = s * __expf(m - mn) + s2 * __expf(m2 - mn);
    m = mn;
  }
  __shared__ float rm[4], rs[4];
  if ((threadIdx.x & 63) == 0) { rm[threadIdx.x >> 6] = m; rs[threadIdx.x >> 6] = s; }
  __syncthreads();
  if (threadIdx.x == 0) {
    float M = fmaxf(fmaxf(rm[0], rm[1]), fmaxf(rm[2], rm[3]));
    float S = rs[0] * __expf(rm[0] - M) + rs[1] * __expf(rm[1] - M) +
              rs[2] * __expf(rm[2] - M) + rs[3] * __expf(rm[3] - M);
    nll[r] = M + __logf(S) - row[labels[b * S_ + t + 1]];
  }
}

__global__ __launch_bounds__(256) void reduce_loss(const float* __restrict__ nll,
                                                   float* __restrict__ out) {
  float s = 0.f;
  for (int i = threadIdx.x; i < NROWS; i += 256) s += nll[i];
#pragma unroll
  for (int o = 32; o > 0; o >>= 1) s += __shfl_xor(s, o);
  __shared__ float sb[4];
  if ((threadIdx.x & 63) == 0) sb[threadIdx.x >> 6] = s;
  __syncthreads();
  if (threadIdx.x == 0) out[0] = (sb[0] + sb[1] + sb[2] + sb[3]) / (float)NROWS;
}

// ---------------------------------------------------------------- launch
extern "C" void kernel_launch(void* const* d_in, const int* in_sizes, int n_in,
                              void* d_out, int out_size, void* d_ws,
                              size_t ws_size, hipStream_t stream) {
  const float* h = (const float*)d_in[0];
  const float* Wf = (const float*)d_in[1];
  const int* labels = (const int*)d_in[2];
  float* out = (float*)d_out;
  float* logits = out + 1;

  const size_t abytes = (size_t)M_ * K_ * 2;
  const size_t bbytes = (size_t)N_ * K_ * 2;
  const size_t need = abytes + bbytes + (size_t)NROWS * sizeof(float);

  if (ws_size >= need) {
    unsigned char* base = (unsigned char*)d_ws;
    __bf16* hA = (__bf16*)base;
    __bf16* wB = (__bf16*)(base + abytes);
    float* nll = (float*)(base + abytes + bbytes);
    cvt_f32_to_bf16<<<2048, 256, 0, stream>>>(h, (bf16x8*)hA,
                                              (long)((size_t)M_ * K_ / 8));
    cvt_f32_to_bf16<<<4096, 256, 0, stream>>>(Wf, (bf16x8*)wB,
                                              (long)((size_t)N_ * K_ / 8));
    gemm256<<<2000, 512, 0, stream>>>(hA, wB, logits);
    ce_rows<<<4094, 256, 0, stream>>>(logits, labels, nll);
    reduce_loss<<<1, 256, 0, stream>>>(nll, out);
  } else {
    float* nll = (float*)d_ws;
    gemm_fb<<<8000, 256, 0, stream>>>(h, Wf, logits);
    ce_rows<<<4094, 256, 0, stream>>>(logits, labels, nll);
    reduce_loss<<<1, 256, 0, stream>>>(nll, out);
  }
}

// Round 7
// 1197.859 us; speedup vs baseline: 1.0496x; 1.0496x over previous
//
#include <hip/hip_runtime.h>
#include <hip/hip_bf16.h>

#define M_ 4096
#define N_ 32000
#define K_ 4096
#define S_ 2048
#define SM1 2047
#define NROWS 4094
#define NT_ 64   // K-tiles of BK=64
#define NB_ 125  // n-blocks per row

typedef __bf16 bf16x8 __attribute__((ext_vector_type(8)));
typedef float f32x4 __attribute__((ext_vector_type(4)));

#define GLDS16(g, l)                                                         \
  __builtin_amdgcn_global_load_lds(                                          \
      (__attribute__((address_space(1))) const void*)(g),                    \
      (__attribute__((address_space(3))) void*)(l), 16, 0, 0)
#define BAR() __builtin_amdgcn_s_barrier()
#define PRIO1() __builtin_amdgcn_s_setprio(1)
#define PRIO0() __builtin_amdgcn_s_setprio(0)
#define VMCNT(n) asm volatile("s_waitcnt vmcnt(" #n ")" ::: "memory")

// ---------------------------------------------------------------- cvt kernel
__global__ __launch_bounds__(256) void cvt_f32_to_bf16(
    const float* __restrict__ in, bf16x8* __restrict__ out, long n8) {
  long i0 = (long)blockIdx.x * blockDim.x + threadIdx.x;
  long stride = (long)gridDim.x * blockDim.x;
  for (long i = i0; i < n8; i += stride) {
    const float4* p = reinterpret_cast<const float4*>(in) + i * 2;
    float4 a = p[0];
    float4 b = p[1];
    bf16x8 v;
    v[0] = (__bf16)a.x; v[1] = (__bf16)a.y; v[2] = (__bf16)a.z; v[3] = (__bf16)a.w;
    v[4] = (__bf16)b.x; v[5] = (__bf16)b.y; v[6] = (__bf16)b.z; v[7] = (__bf16)b.w;
    out[i] = v;
  }
}

// ---------------------------------------------------------------- GEMM 256x256, BK=64, v4 deep-lead schedule
// C[m,n] = sum_k A[m,k]*B[n,k]. 512 thr = 8 waves (2m x 4n), per-wave 128x64
// = acc[8][4]. LDS 2 x 64KB (A 32K | B 32K), 128-B rows, slot = c ^ (row&7)
// (measured-conflict-free: linear GLDS dest + inverse-swz source).
//
// Halfsets (2 GLDS/thread each):
//   SA0 = A rows bit6==0 (a_lo)   SA1 = A rows bit6==1 (a_hi)
//   SB0 = B rows bit5==0 (b0)     SB1 = B rows bit5==1 (b1)
// v4: every stage is >=3 phases old at its covering wait. Tile s:
//   ph1: stage SA1(s+1); MFMA al*b0;      VMCNT(6) [SA1,SB1(s) aged 3-4ph]; BAR
//   ph2: stage SB1(s+1); read b1r,ah(s);  MFMA al*b1; BAR
//   ph3: (no stage);     MFMA ah*b0;      VMCNT(4) [SA0,SB0(s+1) aged 3-4ph]; BAR
//   ph4: stage SA0,SB0(s+2) -> buf cur;   read al,b0r(s+1); MFMA ah*b1; BAR
// Queue audit (in-order, 2 loads/halfset): at ph1-end outstanding =
// [SA1(s),SB1(s),SA0SB0(s+1),SA1(s+1)] = 10 -> VMCNT(6) retires SA1,SB1(s).
// At ph3-end = [SA0SB0(s+1),SA1(s+1),SB1(s+1)] = 8 -> VMCNT(4) retires
// SA0,SB0(s+1). Tail: s=NT-2 skips ph4 stage; s=NT-1: ph1 VMCNT(0), ph3 skip.
// WAR: ph4's stage into cur.SA0/SB0 — those regions' last ds_reads (al,b0r(s)
// at ph4(s-1)) completed before ph1(s) MFMA, 3 barriers earlier, all waves.
// Collective rule everywhere: VMCNT -> BAR -> read.
//
// Fused CE epilogue: per-row (max, sum exp) over this block's 256-col tile,
// written to pm/ps [4096][125] for ce_combine.
__global__ __launch_bounds__(512, 2) void gemm256(
    const __bf16* __restrict__ A, const __bf16* __restrict__ B,
    float* __restrict__ C, float* __restrict__ pm, float* __restrict__ ps) {
  __shared__ __align__(1024) unsigned char smem[2][65536];

  const int tid = threadIdx.x;
  const int bid = blockIdx.x;
  // Bijective XCD swizzle (2000 % 8 == 0), n-panel-major within XCD.
  const int wg = (bid & 7) * 250 + (bid >> 3);
  const int nblk = wg >> 4;  // 0..124
  const int mblk = wg & 15;  // 0..15
  const int m0 = mblk * 256;
  const int n0 = nblk * 256;

  const int w = tid >> 6;
  const int lane = tid & 63;
  const int wm = w >> 2;  // 0..1
  const int wn = w & 3;   // 0..3
  const int rl = lane & 15;
  const int cl = lane >> 4;
  const int srow = tid >> 3;  // staging row-within-64 block
  const int scc = tid & 7;    // staging dest chunk

  f32x4 acc[8][4];
#pragma unroll
  for (int i = 0; i < 8; ++i)
#pragma unroll
    for (int j = 0; j < 4; ++j) acc[i][j] = (f32x4){0.f, 0.f, 0.f, 0.f};

  // A halfset q: 64-row blocks at q*64 and 128+q*64.
  auto stA2 = [&](int nbuf, int kt, int q) {
#pragma unroll
    for (int j = 0; j < 2; ++j) {
      const int r0 = q * 64 + j * 128;
      const int row = r0 + srow;
      const int c = scc ^ (row & 7);
      GLDS16(A + (size_t)(m0 + row) * K_ + kt * 64 + c * 8,
             &smem[nbuf][r0 * 128 + tid * 16]);
    }
  };
  // B halfset q: 32-row stripes at {0,64,128,192}+q*32.
  auto stB2 = [&](int nbuf, int kt, int q) {
#pragma unroll
    for (int j = 0; j < 2; ++j) {
      const int cg = j * 512 + tid;
      const int rl_ = cg >> 3;
      const int row = ((rl_ >> 5) << 6) + q * 32 + (rl_ & 31);
      const int cc = cg & 7;
      const int c = cc ^ (row & 7);
      GLDS16(B + (size_t)(n0 + row) * K_ + kt * 64 + c * 8,
             &smem[nbuf][32768 + row * 128 + cc * 16]);
    }
  };
  auto ld = [&](const unsigned char* base, int row, int c) -> bf16x8 {
    return *(const bf16x8*)(base + row * 128 + (((c ^ row) & 7) << 4));
  };

  // Prologue: tile0 (4 halfsets) + SA0,SB0(1); wait first 4 halfsets... need
  // only SA0,SB0(0) -> VMCNT(8) retires them (12 issued, keep 8 newest).
  stA2(0, 0, 0); stB2(0, 0, 0); stA2(0, 0, 1); stB2(0, 0, 1);
  stA2(1, 1, 0); stB2(1, 1, 0);
  VMCNT(8);
  BAR();

  bf16x8 al[4][2], ah[4][2], b0r[2][2], b1r[2][2];
#pragma unroll
  for (int jj = 0; jj < 2; ++jj)
#pragma unroll
    for (int ks = 0; ks < 2; ++ks)
      b0r[jj][ks] = ld(smem[0] + 32768, wn * 64 + jj * 16 + rl, ks * 4 + cl);
#pragma unroll
  for (int ii = 0; ii < 4; ++ii)
#pragma unroll
    for (int ks = 0; ks < 2; ++ks)
      al[ii][ks] = ld(smem[0], wm * 128 + ii * 16 + rl, ks * 4 + cl);

  for (int s = 0; s < NT_; ++s) {
    const int cur = s & 1;
    const int nxt = cur ^ 1;
    const unsigned char* bA = smem[cur];
    const unsigned char* bB = smem[cur] + 32768;
    const bool st = (s + 1 < NT_);

    // ---- ph1: stage SA1(s+1); MFMA a_lo x b0; VMCNT(6) [SA1,SB1(s)]
    if (st) stA2(nxt, s + 1, 1);
    PRIO1();
#pragma unroll
    for (int ii = 0; ii < 4; ++ii)
#pragma unroll
      for (int jj = 0; jj < 2; ++jj)
#pragma unroll
        for (int ks = 0; ks < 2; ++ks)
          acc[ii][jj] = __builtin_amdgcn_mfma_f32_16x16x32_bf16(
              al[ii][ks], b0r[jj][ks], acc[ii][jj], 0, 0, 0);
    PRIO0();
    if (st) { VMCNT(6); } else { VMCNT(0); }
    BAR();

    // ---- ph2: stage SB1(s+1); read b1(first)+a_hi; MFMA a_lo x b1
    if (st) stB2(nxt, s + 1, 1);
#pragma unroll
    for (int jj = 0; jj < 2; ++jj)
#pragma unroll
      for (int ks = 0; ks < 2; ++ks)
        b1r[jj][ks] = ld(bB, wn * 64 + 32 + jj * 16 + rl, ks * 4 + cl);
#pragma unroll
    for (int ii = 0; ii < 4; ++ii)
#pragma unroll
      for (int ks = 0; ks < 2; ++ks)
        ah[ii][ks] = ld(bA, wm * 128 + 64 + ii * 16 + rl, ks * 4 + cl);
    PRIO1();
#pragma unroll
    for (int ii = 0; ii < 4; ++ii)
#pragma unroll
      for (int jj = 0; jj < 2; ++jj)
#pragma unroll
        for (int ks = 0; ks < 2; ++ks)
          acc[ii][2 + jj] = __builtin_amdgcn_mfma_f32_16x16x32_bf16(
              al[ii][ks], b1r[jj][ks], acc[ii][2 + jj], 0, 0, 0);
    PRIO0();
    BAR();

    // ---- ph3: MFMA a_hi x b0; VMCNT(4) [SA0,SB0(s+1)]
    PRIO1();
#pragma unroll
    for (int ii = 0; ii < 4; ++ii)
#pragma unroll
      for (int jj = 0; jj < 2; ++jj)
#pragma unroll
        for (int ks = 0; ks < 2; ++ks)
          acc[4 + ii][jj] = __builtin_amdgcn_mfma_f32_16x16x32_bf16(
              ah[ii][ks], b0r[jj][ks], acc[4 + ii][jj], 0, 0, 0);
    PRIO0();
    if (st) VMCNT(4);
    BAR();

    // ---- ph4: stage SA0,SB0(s+2) into cur; read next al,b0 (drain under
    //           MFMA); MFMA a_hi x b1; BAR
    if (s + 2 < NT_) { stA2(cur, s + 2, 0); stB2(cur, s + 2, 0); }
    if (st) {
      const unsigned char* nA = smem[nxt];
      const unsigned char* nB = smem[nxt] + 32768;
#pragma unroll
      for (int jj = 0; jj < 2; ++jj)
#pragma unroll
        for (int ks = 0; ks < 2; ++ks)
          b0r[jj][ks] = ld(nB, wn * 64 + jj * 16 + rl, ks * 4 + cl);
#pragma unroll
      for (int ii = 0; ii < 4; ++ii)
#pragma unroll
        for (int ks = 0; ks < 2; ++ks)
          al[ii][ks] = ld(nA, wm * 128 + ii * 16 + rl, ks * 4 + cl);
    }
    PRIO1();
#pragma unroll
    for (int ii = 0; ii < 4; ++ii)
#pragma unroll
      for (int jj = 0; jj < 2; ++jj)
#pragma unroll
        for (int ks = 0; ks < 2; ++ks)
          acc[4 + ii][2 + jj] = __builtin_amdgcn_mfma_f32_16x16x32_bf16(
              ah[ii][ks], b1r[jj][ks], acc[4 + ii][2 + jj], 0, 0, 0);
    PRIO0();
    BAR();
  }

  // Epilogue: C/D layout col = lane&15, row = (lane>>4)*4 + reg  [m89]
#pragma unroll
  for (int i = 0; i < 8; ++i)
#pragma unroll
    for (int j = 0; j < 4; ++j)
#pragma unroll
      for (int r = 0; r < 4; ++r) {
        const int grow = m0 + wm * 128 + i * 16 + cl * 4 + r;
        const int gcol = n0 + wn * 64 + j * 16 + rl;
        C[(size_t)grow * N_ + gcol] = acc[i][j][r];
      }

  // ---- fused CE partials: per-row max & exp-sum over this 256-col tile.
  // Thread holds rows (wm*128+i*16+cl*4+r), cols (wn*64+j*16+rl): 4 cols/row.
  float* red = (float*)smem;          // [4][256] per-wn row maxes (4 KB)
  float* red2 = (float*)(smem[0] + 4096);  // [4][256] per-wn row sums
  float fmx[8][4];
  {
    BAR();  // K-loop fully done in all waves before LDS reuse
#pragma unroll
    for (int i = 0; i < 8; ++i)
#pragma unroll
      for (int r = 0; r < 4; ++r) {
        float v = fmaxf(fmaxf(acc[i][0][r], acc[i][1][r]),
                        fmaxf(acc[i][2][r], acc[i][3][r]));
#pragma unroll
        for (int o = 1; o < 16; o <<= 1) v = fmaxf(v, __shfl_xor(v, o));
        if (rl == 0) red[wn * 256 + wm * 128 + i * 16 + cl * 4 + r] = v;
      }
    BAR();
#pragma unroll
    for (int i = 0; i < 8; ++i)
#pragma unroll
      for (int r = 0; r < 4; ++r) {
        const int row = wm * 128 + i * 16 + cl * 4 + r;
        fmx[i][r] = fmaxf(fmaxf(red[row], red[256 + row]),
                          fmaxf(red[512 + row], red[768 + row]));
        float sv = __expf(acc[i][0][r] - fmx[i][r]) +
                   __expf(acc[i][1][r] - fmx[i][r]) +
                   __expf(acc[i][2][r] - fmx[i][r]) +
                   __expf(acc[i][3][r] - fmx[i][r]);
#pragma unroll
        for (int o = 1; o < 16; o <<= 1) sv += __shfl_xor(sv, o);
        if (rl == 0) red2[wn * 256 + row] = sv;
      }
    BAR();
    if (tid < 256) {
      const int row = tid;
      const float Mv = fmaxf(fmaxf(red[row], red[256 + row]),
                             fmaxf(red[512 + row], red[768 + row]));
      const float Sv = red2[row] + red2[256 + row] + red2[512 + row] +
                       red2[768 + row];
      pm[(size_t)(m0 + row) * NB_ + nblk] = Mv;
      ps[(size_t)(m0 + row) * NB_ + nblk] = Sv;
    }
  }
}

// ---------------------------------------------------------------- CE combine
__global__ __launch_bounds__(64) void ce_combine(
    const float* __restrict__ pm, const float* __restrict__ ps,
    const float* __restrict__ logits, const int* __restrict__ labels,
    float* __restrict__ nll) {
  const int r = blockIdx.x;  // 0..4093
  const int b = r / SM1;
  const int t = r - b * SM1;
  const int m = b * S_ + t;
  const int lane = threadIdx.x;
  float M = -3.4e38f, Ssum = 0.f;
  for (int j = lane; j < NB_; j += 64) {
    const float mj = pm[(size_t)m * NB_ + j];
    const float sj = ps[(size_t)m * NB_ + j];
    if (mj > M) { Ssum *= __expf(M - mj); M = mj; }
    Ssum += sj * __expf(mj - M);
  }
#pragma unroll
  for (int o = 32; o > 0; o >>= 1) {
    const float M2 = __shfl_xor(M, o), S2 = __shfl_xor(Ssum, o);
    const float mn = fmaxf(M, M2);
    Ssum = Ssum * __expf(M - mn) + S2 * __expf(M2 - mn);
    M = mn;
  }
  if (lane == 0) {
    const int lbl = labels[b * S_ + t + 1];
    nll[r] = M + __logf(Ssum) - logits[(size_t)m * N_ + lbl];
  }
}

// ---------------------------------------------------------------- fallback GEMM (fp32 in, 128^2)
__global__ __launch_bounds__(256) void gemm_fb(const float* __restrict__ Ap,
                                               const float* __restrict__ Bp,
                                               float* __restrict__ Cp) {
  __shared__ __align__(1024) unsigned char smem[2][16384];
  const int tid = threadIdx.x;
  const int bid = blockIdx.x;
  const int swz = (bid & 7) * 1000 + (bid >> 3);
  const int nblk = swz >> 5;
  const int mblk = swz & 31;
  const int m0 = mblk * 128;
  const int n0 = nblk * 128;
  const int w = tid >> 6, lane = tid & 63;
  const int wm = w >> 1, wn = w & 1;
  const int rl = lane & 15, cl = lane >> 4;

  f32x4 acc[4][4];
#pragma unroll
  for (int i = 0; i < 4; ++i)
#pragma unroll
    for (int j = 0; j < 4; ++j) acc[i][j] = (f32x4){0.f, 0.f, 0.f, 0.f};

  auto stage = [&](int buf, int kt) {
    const int k0 = kt * 32;
#pragma unroll
    for (int j = 0; j < 2; ++j) {
      const int t = j * 256 + tid;
      const int row = t >> 2;
      const int c = t & 3;
      const int rp = row >> 1;
      const int pp = ((row & 1) * 4 + c) ^ (rp & 7);
      const int lb = rp * 128 + pp * 16;
      {
        const float4* g = (const float4*)(Ap + (size_t)(m0 + row) * K_ + k0 + c * 8);
        float4 x = g[0], y = g[1];
        bf16x8 v;
        v[0] = (__bf16)x.x; v[1] = (__bf16)x.y; v[2] = (__bf16)x.z; v[3] = (__bf16)x.w;
        v[4] = (__bf16)y.x; v[5] = (__bf16)y.y; v[6] = (__bf16)y.z; v[7] = (__bf16)y.w;
        *(bf16x8*)(&smem[buf][lb]) = v;
      }
      {
        const float4* g = (const float4*)(Bp + (size_t)(n0 + row) * K_ + k0 + c * 8);
        float4 x = g[0], y = g[1];
        bf16x8 v;
        v[0] = (__bf16)x.x; v[1] = (__bf16)x.y; v[2] = (__bf16)x.z; v[3] = (__bf16)x.w;
        v[4] = (__bf16)y.x; v[5] = (__bf16)y.y; v[6] = (__bf16)y.z; v[7] = (__bf16)y.w;
        *(bf16x8*)(&smem[buf][8192 + lb]) = v;
      }
    }
  };
  auto ldfrag = [&](const unsigned char* base, int row, int c) -> bf16x8 {
    const int rp = row >> 1;
    const int pp = ((row & 1) * 4 + c) ^ (rp & 7);
    return *(const bf16x8*)(base + rp * 128 + pp * 16);
  };
  auto compute = [&](int buf) {
    const unsigned char* bA = smem[buf];
    const unsigned char* bB = smem[buf] + 8192;
    bf16x8 af[4], bfv[4];
#pragma unroll
    for (int i = 0; i < 4; ++i) af[i] = ldfrag(bA, wm * 64 + i * 16 + rl, cl);
#pragma unroll
    for (int j = 0; j < 4; ++j) bfv[j] = ldfrag(bB, wn * 64 + j * 16 + rl, cl);
#pragma unroll
    for (int i = 0; i < 4; ++i)
#pragma unroll
      for (int j = 0; j < 4; ++j)
        acc[i][j] = __builtin_amdgcn_mfma_f32_16x16x32_bf16(af[i], bfv[j],
                                                            acc[i][j], 0, 0, 0);
  };

  stage(0, 0);
  __syncthreads();
  for (int kt = 0; kt < 128; kt += 2) {
    if (kt + 1 < 128) stage(1, kt + 1);
    compute(0);
    __syncthreads();
    if (kt + 2 < 128) stage(0, kt + 2);
    compute(1);
    __syncthreads();
  }
#pragma unroll
  for (int i = 0; i < 4; ++i)
#pragma unroll
    for (int j = 0; j < 4; ++j)
#pragma unroll
      for (int r = 0; r < 4; ++r) {
        const int grow = m0 + wm * 64 + i * 16 + cl * 4 + r;
        const int gcol = n0 + wn * 64 + j * 16 + rl;
        Cp[(size_t)grow * N_ + gcol] = acc[i][j][r];
      }
}

// ---------------------------------------------------------------- CE loss (fallback, online 1-pass)
__global__ __launch_bounds__(256) void ce_rows(const float* __restrict__ logits,
                                               const int* __restrict__ labels,
                                               float* __restrict__ nll) {
  const int r = blockIdx.x;
  const int b = r / SM1;
  const int t = r - b * SM1;
  const float* row = logits + (size_t)(b * S_ + t) * N_;
  float m = -3.4e38f, s = 0.f;
  const float4* row4 = (const float4*)row;
  for (int i = threadIdx.x; i < 7936; i += 256) {
    float4 v = row4[i];
    float mx = fmaxf(fmaxf(v.x, v.y), fmaxf(v.z, v.w));
    if (mx > m) { s *= __expf(m - mx); m = mx; }
    s += __expf(v.x - m) + __expf(v.y - m) + __expf(v.z - m) + __expf(v.w - m);
  }
  {
    float v = row[31744 + threadIdx.x];
    if (v > m) { s *= __expf(m - v); m = v; }
    s += __expf(v - m);
  }
#pragma unroll
  for (int o = 32; o > 0; o >>= 1) {
    float m2 = __shfl_xor(m, o), s2 = __shfl_xor(s, o);
    float mn = fmaxf(m, m2);
    s = s * __expf(m - mn) + s2 * __expf(m2 - mn);
    m = mn;
  }
  __shared__ float rm[4], rs[4];
  if ((threadIdx.x & 63) == 0) { rm[threadIdx.x >> 6] = m; rs[threadIdx.x >> 6] = s; }
  __syncthreads();
  if (threadIdx.x == 0) {
    float M = fmaxf(fmaxf(rm[0], rm[1]), fmaxf(rm[2], rm[3]));
    float S = rs[0] * __expf(rm[0] - M) + rs[1] * __expf(rm[1] - M) +
              rs[2] * __expf(rm[2] - M) + rs[3] * __expf(rm[3] - M);
    nll[r] = M + __logf(S) - row[labels[b * S_ + t + 1]];
  }
}

__global__ __launch_bounds__(256) void reduce_loss(const float* __restrict__ nll,
                                                   float* __restrict__ out) {
  float s = 0.f;
  for (int i = threadIdx.x; i < NROWS; i += 256) s += nll[i];
#pragma unroll
  for (int o = 32; o > 0; o >>= 1) s += __shfl_xor(s, o);
  __shared__ float sb[4];
  if ((threadIdx.x & 63) == 0) sb[threadIdx.x >> 6] = s;
  __syncthreads();
  if (threadIdx.x == 0) out[0] = (sb[0] + sb[1] + sb[2] + sb[3]) / (float)NROWS;
}

// ---------------------------------------------------------------- launch
extern "C" void kernel_launch(void* const* d_in, const int* in_sizes, int n_in,
                              void* d_out, int out_size, void* d_ws,
                              size_t ws_size, hipStream_t stream) {
  const float* h = (const float*)d_in[0];
  const float* Wf = (const float*)d_in[1];
  const int* labels = (const int*)d_in[2];
  float* out = (float*)d_out;
  float* logits = out + 1;

  const size_t abytes = (size_t)M_ * K_ * 2;       // 33,554,432
  const size_t bbytes = (size_t)N_ * K_ * 2;       // 262,144,000
  const size_t pbytes = (size_t)M_ * NB_ * 4;      // 2,048,000
  const size_t need = abytes + bbytes + 2 * pbytes + (size_t)NROWS * 4;

  if (ws_size >= need) {
    unsigned char* base = (unsigned char*)d_ws;
    __bf16* hA = (__bf16*)base;
    __bf16* wB = (__bf16*)(base + abytes);
    float* pm = (float*)(base + abytes + bbytes);
    float* psum = (float*)(base + abytes + bbytes + pbytes);
    float* nll = (float*)(base + abytes + bbytes + 2 * pbytes);
    cvt_f32_to_bf16<<<2048, 256, 0, stream>>>(h, (bf16x8*)hA,
                                              (long)((size_t)M_ * K_ / 8));
    cvt_f32_to_bf16<<<4096, 256, 0, stream>>>(Wf, (bf16x8*)wB,
                                              (long)((size_t)N_ * K_ / 8));
    gemm256<<<2000, 512, 0, stream>>>(hA, wB, logits, pm, psum);
    ce_combine<<<NROWS, 64, 0, stream>>>(pm, psum, logits, labels, nll);
    reduce_loss<<<1, 256, 0, stream>>>(nll, out);
  } else {
    float* nll = (float*)d_ws;
    gemm_fb<<<8000, 256, 0, stream>>>(h, Wf, logits);
    ce_rows<<<4094, 256, 0, stream>>>(logits, labels, nll);
    reduce_loss<<<1, 256, 0, stream>>>(nll, out);
  }
}